// Round 10
// baseline (177.757 us; speedup 1.0000x reference)
//
#include <hip/hip_runtime.h>
#include <hip/hip_bf16.h>

// Causal self-attention: qkv = x@w_qkv + b_qkv; flash-attn (causal); out = att@w_proj + b_proj
// B=4, T=2048, C=1024, H=16, D=64. All matmuls bf16 MFMA 16x16x32, fp32 accumulate.
// R9: GEMM rebuilt as an 8-phase counted-vmcnt pipeline (T3+T4+T5):
//     - BK=64 as two K-halves; LDS [buf][kh][128][32] per operand (64 KB total).
//     - per phase: ds_read next-phase frags | stage ONE (op,kh) chunk (2 gload_lds)
//       | 8 MFMA | vmcnt(4) | raw s_barrier | sched_barrier(0).
//     - stage lag 5 phases; vmcnt(4) guarantees stages <= p-3 landed at phase p.
//     - NO __syncthreads in the K-loop (its vmcnt(0) drain is the m97 ~20% stall).
//     Flash: r5/r9-proven version, untouched.

typedef __bf16 bf16x8 __attribute__((ext_vector_type(8)));
typedef float f32x4 __attribute__((ext_vector_type(4)));
typedef unsigned short u16x8 __attribute__((ext_vector_type(8)));
typedef unsigned short u16x4 __attribute__((ext_vector_type(4)));
typedef unsigned int u32;

#define LOG2E 1.44269504088896340736f
#define NEG_INF (-__builtin_inff())

#define AS_GLOBAL(p) ((const __attribute__((address_space(1))) u32*)(p))
#define AS_LDS(p) ((__attribute__((address_space(3))) u32*)(p))

__device__ __forceinline__ unsigned short f2bf(float f) {
  unsigned int u = __builtin_bit_cast(unsigned int, f);
  u += 0x7fff + ((u >> 16) & 1);   // RNE
  return (unsigned short)(u >> 16);
}

__device__ __forceinline__ u32 cvt_pk_bf16(float lo, float hi) {
  u32 r;
  asm("v_cvt_pk_bf16_f32 %0, %1, %2" : "=v"(r) : "v"(lo), "v"(hi));
  return r;
}

__device__ __forceinline__ bf16x8 ld_frag(const unsigned short* p) {
  return __builtin_bit_cast(bf16x8, *reinterpret_cast<const u16x8*>(p));
}

// ---- fp32 -> bf16 elementwise (x) ----
__global__ void k_convert(const float* __restrict__ in, unsigned short* __restrict__ out, int n4) {
  int i = blockIdx.x * blockDim.x + threadIdx.x;
  int stride = gridDim.x * blockDim.x;
  for (; i < n4; i += stride) {
    float4 v = reinterpret_cast<const float4*>(in)[i];
    u16x4 o = { f2bf(v.x), f2bf(v.y), f2bf(v.z), f2bf(v.w) };
    reinterpret_cast<u16x4*>(out)[i] = o;
  }
}

// ---- fp32 [K][N] -> bf16 [N][K] transpose; rows n < scaleN of output scaled by scl ----
__global__ void k_transpose(const float* __restrict__ in, unsigned short* __restrict__ out,
                            int K, int N, int scaleN, float scl) {
  __shared__ float tile[32][33];
  int n0 = blockIdx.x * 32, k0 = blockIdx.y * 32;
  int tx = threadIdx.x & 31, ty = threadIdx.x >> 5;  // 32 x 8
#pragma unroll
  for (int i = 0; i < 4; i++)
    tile[ty + i * 8][tx] = in[(size_t)(k0 + ty + i * 8) * N + n0 + tx];
  __syncthreads();
#pragma unroll
  for (int i = 0; i < 4; i++) {
    int n = n0 + ty + i * 8;
    float v = tile[tx][ty + i * 8];
    if (n < scaleN) v *= scl;
    out[(size_t)n * K + k0 + tx] = f2bf(v);
  }
}

// ---- bias prep: first scaleN entries scaled ----
__global__ void k_scale_bias(const float* __restrict__ in, float* __restrict__ out,
                             int n, int scaleN, float scl) {
  int i = blockIdx.x * blockDim.x + threadIdx.x;
  if (i < n) out[i] = (i < scaleN) ? in[i] * scl : in[i];
}

// ---- bf16 GEMM, 8-phase pipeline: C[M][N] = A[M][K] @ Bt[N][K]^T + bias ----
// LDS plane (row, slot) holds global (row, slot ^ ((row>>2)&3)); slot = 8-elem (16B).
#define GVMCNT4 asm volatile("s_waitcnt vmcnt(4)")
#define GBAR { __builtin_amdgcn_s_barrier(); __builtin_amdgcn_sched_barrier(0); }
#define MFMA8(MB, AF, BF) \
  { __builtin_amdgcn_s_setprio(1); \
    _Pragma("unroll") for (int n_ = 0; n_ < 4; ++n_) { \
      acc[MB][n_]     = __builtin_amdgcn_mfma_f32_16x16x32_bf16(AF[0], BF[n_], acc[MB][n_], 0, 0, 0); \
      acc[MB + 1][n_] = __builtin_amdgcn_mfma_f32_16x16x32_bf16(AF[1], BF[n_], acc[MB + 1][n_], 0, 0, 0); \
    } __builtin_amdgcn_s_setprio(0); }

template <bool BF16_OUT>
__global__ __launch_bounds__(256, 2) void k_gemm(
    const unsigned short* __restrict__ A, const unsigned short* __restrict__ Bt,
    const float* __restrict__ bias, void* __restrict__ Cv, int M, int N, int K) {
  __shared__ unsigned short Asm[2][2][128][32];  // [buf][kh][row][col]
  __shared__ unsigned short Bsm[2][2][128][32];
  const int tid = threadIdx.x;
  const int lane = tid & 63, w = tid >> 6;
  const int wr = w >> 1, wc = w & 1;
  const int brow = blockIdx.x * 128, bcol = blockIdx.y * 128;
  const int r0 = lane & 15, kq = lane >> 4;
  const int rswz = (r0 >> 2) & 3;
  const int rdslot = (kq ^ rswz) * 8;

  // staging: wave w covers rows w*32..w*32+31 of a 128x32 plane (2 loads/thread)
  const int srow = w * 32 + (lane >> 2);
  const int sslot = ((lane & 3) ^ ((lane >> 4) & 3)) * 8;
  const unsigned short* aSrc = A + (size_t)(brow + srow) * K + sslot;
  const unsigned short* bSrc = Bt + (size_t)(bcol + srow) * K + sslot;

  f32x4 acc[4][4] = {};
  const int NT = K >> 6;  // 16

#define STAGEA(BUF, KH, TS)                                                              \
  { int kc_ = (TS) * 64 + (KH) * 32;                                                     \
    __builtin_amdgcn_global_load_lds(AS_GLOBAL(aSrc + kc_), AS_LDS(&Asm[BUF][KH][w * 32][0]), 16, 0, 0); \
    __builtin_amdgcn_global_load_lds(AS_GLOBAL(aSrc + kc_ + (size_t)16 * K), AS_LDS(&Asm[BUF][KH][w * 32 + 16][0]), 16, 0, 0); }
#define STAGEB(BUF, KH, TS)                                                              \
  { int kc_ = (TS) * 64 + (KH) * 32;                                                     \
    __builtin_amdgcn_global_load_lds(AS_GLOBAL(bSrc + kc_), AS_LDS(&Bsm[BUF][KH][w * 32][0]), 16, 0, 0); \
    __builtin_amdgcn_global_load_lds(AS_GLOBAL(bSrc + kc_ + (size_t)16 * K), AS_LDS(&Bsm[BUF][KH][w * 32 + 16][0]), 16, 0, 0); }
#define LDA(BUF, KH, MM) ld_frag(&Asm[BUF][KH][wr * 64 + (MM) * 16 + r0][rdslot])
#define LDB(BUF, KH, NN) ld_frag(&Bsm[BUF][KH][wc * 64 + (NN) * 16 + r0][rdslot])

  // prologue: stage tile0 fully + tile1 A-kh0; drain; pre-read phase-0 frags
  STAGEA(0, 0, 0); STAGEB(0, 0, 0); STAGEA(0, 1, 0); STAGEB(0, 1, 0); STAGEA(1, 0, 1);
  __syncthreads();

  bf16x8 afA[2], afB[2], bfE[4], bfO[4];
  afA[0] = LDA(0, 0, 0); afA[1] = LDA(0, 0, 1);
#pragma unroll
  for (int n = 0; n < 4; ++n) bfE[n] = LDB(0, 0, n);

  const int NIT = NT >> 1;  // 8
  for (int it = 0; it < NIT; ++it) {
    const int t1 = 2 * it + 1, t2 = 2 * it + 2, t3 = 2 * it + 3;
    const bool g2 = (t2 < NT), g3 = (t3 < NT);
    // ---- c8=0: MFMA buf0 kh0 m0-1; read A kh0 m2-3 (buf0); stage (t1, B-kh0)->buf1
    afB[0] = LDA(0, 0, 2); afB[1] = LDA(0, 0, 3);
    STAGEB(1, 0, t1);
    MFMA8(0, afA, bfE);
    GVMCNT4; GBAR;
    // ---- c8=1: MFMA buf0 kh0 m2-3; read A kh1 m0-1 + B kh1 (buf0); stage (t1, A-kh1)
    afA[0] = LDA(0, 1, 0); afA[1] = LDA(0, 1, 1);
#pragma unroll
    for (int n = 0; n < 4; ++n) bfO[n] = LDB(0, 1, n);
    STAGEA(1, 1, t1);
    MFMA8(2, afB, bfE);
    GVMCNT4; GBAR;
    // ---- c8=2: MFMA buf0 kh1 m0-1; read A kh1 m2-3 (buf0); stage (t1, B-kh1)
    afB[0] = LDA(0, 1, 2); afB[1] = LDA(0, 1, 3);
    STAGEB(1, 1, t1);
    MFMA8(0, afA, bfO);
    GVMCNT4; GBAR;
    // ---- c8=3: MFMA buf0 kh1 m2-3; read buf1 A kh0 m0-1 + B kh0; stage (t2, A-kh0)->buf0
    afA[0] = LDA(1, 0, 0); afA[1] = LDA(1, 0, 1);
#pragma unroll
    for (int n = 0; n < 4; ++n) bfE[n] = LDB(1, 0, n);
    if (g2) STAGEA(0, 0, t2);
    MFMA8(2, afB, bfO);
    GVMCNT4; GBAR;
    // ---- c8=4: MFMA buf1 kh0 m0-1; read buf1 A kh0 m2-3; stage (t2, B-kh0)
    afB[0] = LDA(1, 0, 2); afB[1] = LDA(1, 0, 3);
    if (g2) STAGEB(0, 0, t2);
    MFMA8(0, afA, bfE);
    GVMCNT4; GBAR;
    // ---- c8=5: MFMA buf1 kh0 m2-3; read buf1 A kh1 m0-1 + B kh1; stage (t2, A-kh1)
    afA[0] = LDA(1, 1, 0); afA[1] = LDA(1, 1, 1);
#pragma unroll
    for (int n = 0; n < 4; ++n) bfO[n] = LDB(1, 1, n);
    if (g2) STAGEA(0, 1, t2);
    MFMA8(2, afB, bfE);
    GVMCNT4; GBAR;
    // ---- c8=6: MFMA buf1 kh1 m0-1; read buf1 A kh1 m2-3; stage (t2, B-kh1)
    afB[0] = LDA(1, 1, 2); afB[1] = LDA(1, 1, 3);
    if (g2) STAGEB(0, 1, t2);
    MFMA8(0, afA, bfO);
    GVMCNT4; GBAR;
    // ---- c8=7: MFMA buf1 kh1 m2-3; read next-iter buf0 A kh0 m0-1 + B kh0; stage (t3, A-kh0)->buf1
    if (it + 1 < NIT) {
      afA[0] = LDA(0, 0, 0); afA[1] = LDA(0, 0, 1);
#pragma unroll
      for (int n = 0; n < 4; ++n) bfE[n] = LDB(0, 0, n);
    }
    if (g3) STAGEA(1, 0, t3);
    MFMA8(2, afB, bfO);
    GVMCNT4; GBAR;
  }

  const int orow = kq * 4;
#pragma unroll
  for (int n = 0; n < 4; n++) {
#pragma unroll
    for (int m = 0; m < 4; m++) {
      int col = bcol + wc * 64 + n * 16 + r0;
      float bv = bias[col];
#pragma unroll
      for (int r = 0; r < 4; r++) {
        int row = brow + wr * 64 + m * 16 + orow + r;
        float v = acc[m][n][r] + bv;
        if (BF16_OUT)
          ((unsigned short*)Cv)[(size_t)row * N + col] = f2bf(v);
        else
          ((float*)Cv)[(size_t)row * N + col] = v;
      }
    }
  }
#undef STAGEA
#undef STAGEB
#undef LDA
#undef LDB
}

// ---- causal flash attention: 4 waves x 32 q-rows (2 subtiles), 128-row blocks ----
// (r5-proven version) Q pre-scaled by 0.125*log2e => S^T lands in log2 domain.
__global__ __launch_bounds__(256, 3) void k_flash(const unsigned short* __restrict__ qkv,
                                                  unsigned short* __restrict__ att, int T) {
  constexpr int C3 = 3072, C = 1024;
  __shared__ unsigned short Ksm[2][64][72];   // [buf][tk][d]
  __shared__ unsigned short Vsm[2][64][72];   // [buf][d][tk ^ (d&56)]

  const int tid = threadIdx.x, lane = tid & 63, w = tid >> 6;
  const int bh = blockIdx.x;
  const int qtp = gridDim.y - 1 - blockIdx.y;  // long blocks first
  const int b = bh >> 4, h = bh & 15;
  const int q0 = qtp * 128;
  const int r0 = lane & 15, kq = lane >> 4;

  const size_t rowbase = (size_t)b * T * C3;
  const int qb0 = q0 + w * 32, qb1 = qb0 + 16;

  bf16x8 qf[2][2];
  {
    const unsigned short* qp0 = &qkv[rowbase + (size_t)(qb0 + r0) * C3 + h * 64];
    qf[0][0] = ld_frag(&qp0[kq * 8]);
    qf[0][1] = ld_frag(&qp0[32 + kq * 8]);
    const unsigned short* qp1 = qp0 + (size_t)16 * C3;
    qf[1][0] = ld_frag(&qp1[kq * 8]);
    qf[1][1] = ld_frag(&qp1[32 + kq * 8]);
  }

  f32x4 accO[2][4] = {};
  f32x4 ls4[2] = {{0.f,0.f,0.f,0.f},{0.f,0.f,0.f,0.f}};
  float m_run[2] = {NEG_INF, NEG_INF};

  const int stk = tid >> 3, sd8 = (tid & 7) * 8;
  const unsigned short* kbase = &qkv[rowbase + (size_t)stk * C3 + h * 64 + sd8 + C];
  constexpr size_t PSTRIDE = (size_t)32 * C3;

  u16x8 kreg[2], vreg[2];
  auto LOADT = [&](size_t off) {
#pragma unroll
    for (int p = 0; p < 2; p++) {
      kreg[p] = *reinterpret_cast<const u16x8*>(kbase + off + p * PSTRIDE);
      vreg[p] = *reinterpret_cast<const u16x8*>(kbase + off + p * PSTRIDE + C);
    }
  };
  auto WRITET = [&](int buf) {
#pragma unroll
    for (int p = 0; p < 2; p++) {
      int tkk = p * 32 + stk;
      *reinterpret_cast<u16x8*>(&Ksm[buf][tkk][sd8]) = kreg[p];
      int tkx = tkk ^ sd8;
#pragma unroll
      for (int i = 0; i < 8; i++) Vsm[buf][sd8 + i][tkx] = vreg[p][i];
    }
  };

  auto TILE = [&](int buf, int k0) {
    if (k0 > qb1 + 15) return;   // whole wave past its causal range
    const unsigned short(*Ks)[72] = Ksm[buf];
    const unsigned short(*Vs)[72] = Vsm[buf];

    // S^T = K @ Q^T for both subtiles, K-frags shared
    f32x4 st[2][4];
    __builtin_amdgcn_s_setprio(1);
#pragma unroll
    for (int s = 0; s < 4; s++) {
      bf16x8 kf0 = ld_frag(&Ks[s * 16 + r0][kq * 8]);
      bf16x8 kf1 = ld_frag(&Ks[s * 16 + r0][32 + kq * 8]);
#pragma unroll
      for (int u = 0; u < 2; u++) {
        f32x4 a = {};
        a = __builtin_amdgcn_mfma_f32_16x16x32_bf16(kf0, qf[u][0], a, 0, 0, 0);
        a = __builtin_amdgcn_mfma_f32_16x16x32_bf16(kf1, qf[u][1], a, 0, 0, 0);
        st[u][s] = a;
      }
    }
    __builtin_amdgcn_s_setprio(0);

    // softmax per subtile (in-register, lane-local rows)
    u32 pd[2][2][4];
#pragma unroll
    for (int u = 0; u < 2; u++) {
      const int qbu = u ? qb1 : qb0;
      const int qmy = qbu + r0;
      f32x4 sv[4];
      if (k0 + 63 > qbu) {
#pragma unroll
        for (int s = 0; s < 4; s++)
#pragma unroll
          for (int r = 0; r < 4; r++) {
            int kg = k0 + s * 16 + kq * 4 + r;
            sv[s][r] = (kg > qmy) ? NEG_INF : st[u][s][r];
          }
      } else {
#pragma unroll
        for (int s = 0; s < 4; s++) sv[s] = st[u][s];
      }

      f32x4 m4 = __builtin_elementwise_max(__builtin_elementwise_max(sv[0], sv[1]),
                                           __builtin_elementwise_max(sv[2], sv[3]));
      float mx = fmaxf(fmaxf(m4[0], m4[1]), fmaxf(m4[2], m4[3]));

      if (__any(mx > m_run[u] + 8.f)) {
        mx = fmaxf(mx, __shfl_xor(mx, 16));
        mx = fmaxf(mx, __shfl_xor(mx, 32));
        float mn = fmaxf(m_run[u], mx);
        float corr = exp2f(m_run[u] - mn);
        m_run[u] = mn;
        ls4[u] *= corr;
        float cq[4];
#pragma unroll
        for (int r = 0; r < 4; r++) cq[r] = __shfl(corr, kq * 4 + r);
#pragma unroll
        for (int n = 0; n < 4; n++)
#pragma unroll
          for (int r = 0; r < 4; r++) accO[u][n][r] *= cq[r];
      }

#pragma unroll
      for (int s = 0; s < 4; s++) {
        f32x4 d = sv[s] - m_run[u];
        f32x4 p = { exp2f(d[0]), exp2f(d[1]), exp2f(d[2]), exp2f(d[3]) };
        sv[s] = p;
        ls4[u] += p;
      }
      pd[u][0][0] = cvt_pk_bf16(sv[0][0], sv[0][1]);
      pd[u][0][1] = cvt_pk_bf16(sv[0][2], sv[0][3]);
      pd[u][0][2] = cvt_pk_bf16(sv[1][0], sv[1][1]);
      pd[u][0][3] = cvt_pk_bf16(sv[1][2], sv[1][3]);
      pd[u][1][0] = cvt_pk_bf16(sv[2][0], sv[2][1]);
      pd[u][1][1] = cvt_pk_bf16(sv[2][2], sv[2][3]);
      pd[u][1][2] = cvt_pk_bf16(sv[3][0], sv[3][1]);
      pd[u][1][3] = cvt_pk_bf16(sv[3][2], sv[3][3]);
    }

    // PV for both subtiles, V-frags shared
    __builtin_amdgcn_s_setprio(1);
#pragma unroll
    for (int t = 0; t < 2; t++) {
      bf16x8 pa0 = __builtin_bit_cast(bf16x8, *reinterpret_cast<u16x8*>(pd[0][t]));
      bf16x8 pa1 = __builtin_bit_cast(bf16x8, *reinterpret_cast<u16x8*>(pd[1][t]));
#pragma unroll
      for (int n = 0; n < 4; n++) {
        int d = n * 16 + r0;
        int swzb = d & 56;
        const u16x4 lo = *reinterpret_cast<const u16x4*>(&Vs[d][(t * 32 + kq * 4) ^ swzb]);
        const u16x4 hi = *reinterpret_cast<const u16x4*>(&Vs[d][(t * 32 + 16 + kq * 4) ^ swzb]);
        u16x8 vbw;
#pragma unroll
        for (int i = 0; i < 4; i++) { vbw[i] = lo[i]; vbw[4 + i] = hi[i]; }
        bf16x8 vb = __builtin_bit_cast(bf16x8, vbw);
        accO[0][n] = __builtin_amdgcn_mfma_f32_16x16x32_bf16(pa0, vb, accO[0][n], 0, 0, 0);
        accO[1][n] = __builtin_amdgcn_mfma_f32_16x16x32_bf16(pa1, vb, accO[1][n], 0, 0, 0);
      }
    }
    __builtin_amdgcn_s_setprio(0);
  };

  int buf = 0;
  LOADT(0);
  WRITET(0);
  size_t koff = (size_t)64 * C3;
  const int nkt = (q0 + 128) >> 6;
  for (int kt = 0; kt < nkt - 1; kt++) {
    __syncthreads();
    LOADT(koff);
    koff += (size_t)64 * C3;
    TILE(buf, kt * 64);
    WRITET(buf ^ 1);
    buf ^= 1;
  }
  __syncthreads();
  TILE(buf, (nkt - 1) * 64);

  // epilogue
#pragma unroll
  for (int u = 0; u < 2; u++) {
    const int qbu = u ? qb1 : qb0;
    float l = ls4[u][0] + ls4[u][1] + ls4[u][2] + ls4[u][3];
    l += __shfl_xor(l, 16);
    l += __shfl_xor(l, 32);
    float lr[4];
#pragma unroll
    for (int r = 0; r < 4; r++) lr[r] = 1.f / __shfl(l, kq * 4 + r);
#pragma unroll
    for (int n = 0; n < 4; n++) {
#pragma unroll
      for (int r = 0; r < 4; r++) {
        int qrow = qbu + kq * 4 + r;
        float v = accO[u][n][r] * lr[r];
        att[((size_t)b * T + qrow) * C + h * 64 + n * 16 + r0] = f2bf(v);
      }
    }
  }
}

extern "C" void kernel_launch(void* const* d_in, const int* in_sizes, int n_in,
                              void* d_out, int out_size, void* d_ws, size_t ws_size,
                              hipStream_t stream) {
  const float* x = (const float*)d_in[0];
  const float* w_qkv = (const float*)d_in[1];
  const float* b_qkv = (const float*)d_in[2];
  const float* w_proj = (const float*)d_in[3];
  const float* b_proj = (const float*)d_in[4];

  constexpr int B = 4, T = 2048, C = 1024, C3 = 3072;
  constexpr int M = B * T;  // 8192
  constexpr float SCL = 0.125f * LOG2E;

  unsigned short* x_bf = (unsigned short*)d_ws;            // M*C
  unsigned short* wqkvT = x_bf + (size_t)M * C;            // C3*C
  unsigned short* wprojT = wqkvT + (size_t)C3 * C;         // C*C
  unsigned short* qkv = wprojT + (size_t)C * C;            // M*C3
  unsigned short* att = qkv + (size_t)M * C3;              // M*C
  float* bias_s = (float*)(att + (size_t)M * C);           // C3 floats

  hipLaunchKernelGGL(k_convert, dim3(2048), dim3(256), 0, stream, x, x_bf, M * C / 4);
  hipLaunchKernelGGL(k_transpose, dim3(C3 / 32, C / 32), dim3(256), 0, stream,
                     w_qkv, wqkvT, C, C3, C, SCL);
  hipLaunchKernelGGL(k_transpose, dim3(C / 32, C / 32), dim3(256), 0, stream,
                     w_proj, wprojT, C, C, 0, 1.f);
  hipLaunchKernelGGL(k_scale_bias, dim3((C3 + 255) / 256), dim3(256), 0, stream,
                     b_qkv, bias_s, C3, C, SCL);
  hipLaunchKernelGGL((k_gemm<true>), dim3(M / 128, C3 / 128), dim3(256), 0, stream,
                     x_bf, wqkvT, bias_s, (void*)qkv, M, C3, C);
  hipLaunchKernelGGL(k_flash, dim3(64, 16), dim3(256), 0, stream, qkv, att, T);
  hipLaunchKernelGGL((k_gemm<false>), dim3(M / 128, C / 128), dim3(256), 0, stream,
                     att, wprojT, b_proj, d_out, M, C, C);
}